// Round 2
// baseline (3454.263 us; speedup 1.0000x reference)
//
#include <hip/hip_runtime.h>
#include <math.h>

#define BN 8192
#define ENC 256
#define NCL 32
#define TJ 64              // j-rows per LDS tile
#define BI 32              // i-rows per block (4 waves x 8)
#define RW 8               // i-rows per wave (per lane)
#define LSTR 260           // padded LDS floats per j-row (%4==0, /4 odd -> balanced banks)
#define NTILES (BN / TJ)   // 128
#define SMEM_FLOATS (2 * TJ * LSTR)
#define SMEM_BYTES (SMEM_FLOATS * 4 + 4 * NCL * 4)

// ---------------- K1: per-row sumsq, argmax/max of categorical (identical to round 1) ----------------
__global__ void prep_kernel(const float* __restrict__ enc, const float* __restrict__ cat,
                            float* __restrict__ sq, float* __restrict__ maxg,
                            int* __restrict__ hard) {
    int w = threadIdx.x >> 6, l = threadIdx.x & 63;
    int row = blockIdx.x * 4 + w;
    const float4* e4 = (const float4*)(enc + (size_t)row * ENC);
    float4 v = e4[l];
    float s = v.x * v.x + v.y * v.y + v.z * v.z + v.w * v.w;
    for (int m = 32; m; m >>= 1) s += __shfl_xor(s, m, 64);

    float cv = (l < NCL) ? cat[(size_t)row * NCL + l] : -__builtin_huge_valf();
    int ci = (l < NCL) ? l : 0x7fffffff;
    for (int m = 32; m; m >>= 1) {
        float ov = __shfl_xor(cv, m, 64);
        int oi = __shfl_xor(ci, m, 64);
        if (ov > cv || (ov == cv && oi < ci)) { cv = ov; ci = oi; }
    }
    if (l == 0) { sq[row] = s; maxg[row] = cv; hard[row] = ci; }
}

// ---------------- K2: streaming GEMM + exact top-(k+1) per row with cluster payload ----------------
__global__ __launch_bounds__(256, 1)
void overlap2(const float* __restrict__ enc, const float* __restrict__ sq,
              const float* __restrict__ maxg, const int* __restrict__ hard,
              const int* __restrict__ kptr, float* __restrict__ out) {
    extern __shared__ float smem[];
    float* sB = smem;                          // two TJ*LSTR buffers
    int* sbins = (int*)(smem + SMEM_FLOATS);   // 4 waves x 32 bins

    const int t = threadIdx.x;
    const int l = t & 63;
    const int wu = __builtin_amdgcn_readfirstlane(t >> 6);  // wave id, provably uniform
    const int i_base = blockIdx.x * BI + wu * RW;
    const int K1 = *kptr + 1;                  // 26: keep the 26 smallest

    // per-row top-K1 state: slot = lane (< K1); track current max (=running 26th smallest)
    float cand_d[RW], curT[RW];
    int cand_id[RW], curML[RW];
#pragma unroll
    for (int r = 0; r < RW; ++r) {
        cand_d[r] = __builtin_huge_valf();
        cand_id[r] = 0;
        curT[r] = __builtin_huge_valf();
        curML[r] = 0;
    }

    float sqi[RW];
#pragma unroll
    for (int r = 0; r < RW; ++r) sqi[r] = sq[i_base + r];  // uniform -> scalar loads

    const float* arow = enc + (size_t)i_base * ENC;        // uniform base

    // stage tile 0 into buffer 0
    float4 pre[16];
#pragma unroll
    for (int it = 0; it < 16; ++it) {
        int idx = t + it * 256, r = idx >> 6, c = idx & 63;
        pre[it] = ((const float4*)enc)[(size_t)r * (ENC / 4) + c];
    }
#pragma unroll
    for (int it = 0; it < 16; ++it) {
        int idx = t + it * 256, r = idx >> 6, c = idx & 63;
        *(float4*)(sB + r * LSTR + c * 4) = pre[it];
    }
    __syncthreads();

    for (int tt = 0; tt < NTILES; ++tt) {
        const int buf = tt & 1, nbuf = buf ^ 1;
        const int j0 = tt * TJ;
        const int jn = (tt + 1 < NTILES) ? (tt + 1) * TJ : 0;

        // prefetch next tile into registers (latency covered by compute below)
#pragma unroll
        for (int it = 0; it < 16; ++it) {
            int idx = t + it * 256, r = idx >> 6, c = idx & 63;
            pre[it] = ((const float4*)enc)[(size_t)(jn + r) * (ENC / 4) + c];
        }

        float sqj = sq[j0 + l];
        int cidl = hard[j0 + l];

        // GEMM: lane computes dot(e_i[r], e_j[l]) for r=0..7, k ascending (bit-matches round 1)
        float acc[RW];
#pragma unroll
        for (int r = 0; r < RW; ++r) acc[r] = 0.0f;
        const float* brow = sB + buf * (TJ * LSTR) + l * LSTR;
#pragma unroll 8
        for (int k4 = 0; k4 < ENC; k4 += 4) {
            float4 b = *(const float4*)(brow + k4);
#pragma unroll
            for (int r = 0; r < RW; ++r) {
                const float4 a = *(const float4*)(arow + r * ENC + k4);  // uniform -> s_load
                float s = acc[r];
                s = fmaf(b.x, a.x, s);
                s = fmaf(b.y, a.y, s);
                s = fmaf(b.z, a.z, s);
                s = fmaf(b.w, a.w, s);
                acc[r] = s;
            }
        }

        // sqrt-then-compare (matches ref/round-1 tie semantics), then top-K1 insertion
#pragma unroll
        for (int r = 0; r < RW; ++r) {
            float d = sqrtf(fmaxf(sqi[r] + sqj - 2.0f * acc[r], 0.0f));
            unsigned long long m = __ballot(d < curT[r]);
            while (m) {
                int L = __ffsll(m) - 1;
                m &= m - 1;
                float v = __shfl(d, L, 64);
                if (v < curT[r]) {
                    int cid = __shfl(cidl, L, 64);
                    if (l == curML[r]) { cand_d[r] = v; cand_id[r] = cid; }
                    // recompute running max (+argmax) over the K1 slots
                    float mv = (l < K1) ? cand_d[r] : -1.0f;
                    int mi = l;
                    for (int s = 32; s; s >>= 1) {
                        float ov = __shfl_xor(mv, s, 64);
                        int oi = __shfl_xor(mi, s, 64);
                        if (ov > mv || (ov == mv && oi < mi)) { mv = ov; mi = oi; }
                    }
                    curT[r] = mv; curML[r] = mi;
                    m &= __ballot(d < mv);  // prune survivors against tightened threshold
                }
            }
        }

        // write prefetched tile into the other buffer
#pragma unroll
        for (int it = 0; it < 16; ++it) {
            int idx = t + it * 256, r = idx >> 6, c = idx & 63;
            *(float4*)(sB + nbuf * (TJ * LSTR) + r * LSTR + c * 4) = pre[it];
        }
        __syncthreads();
    }

    // epilogue: thr = max of kept K1, neighbors = kept < thr, bins -> entropy (round-1 identical math)
    int* mybins = sbins + wu * NCL;
#pragma unroll
    for (int r = 0; r < RW; ++r) {
        float mv = (l < K1) ? cand_d[r] : -1.0f;
        for (int s = 32; s; s >>= 1) {
            float ov = __shfl_xor(mv, s, 64);
            mv = (ov > mv) ? ov : mv;
        }
        float thr = mv;
        bool isn = (l < K1) && (cand_d[r] < thr);
        int n = __popcll(__ballot(isn));
        if (l < NCL) mybins[l] = 0;
        if (isn) atomicAdd(&mybins[cand_id[r]], 1);
        int cnt = (l < NCL) ? mybins[l] : 0;
        float nf = (float)n;
        float b = (float)cnt / nf;
        float term = (l < NCL) ? (-b * logf(b + 1e-5f)) : 0.0f;
        if (l < NCL) {
            for (int s = 16; s; s >>= 1) term += __shfl_xor(term, s, 64);
        }
        if (l == 0) out[i_base + r] = term * maxg[i_base + r];
    }
}

extern "C" void kernel_launch(void* const* d_in, const int* in_sizes, int n_in,
                              void* d_out, int out_size, void* d_ws, size_t ws_size,
                              hipStream_t stream) {
    const float* enc = (const float*)d_in[0];
    const float* cat = (const float*)d_in[1];
    const int* kptr = (const int*)d_in[2];
    float* out = (float*)d_out;

    float* sq = (float*)d_ws;
    float* maxg = sq + BN;
    int* hard = (int*)(maxg + BN);

    (void)hipFuncSetAttribute((const void*)overlap2,
                              hipFuncAttributeMaxDynamicSharedMemorySize, SMEM_BYTES);

    prep_kernel<<<BN / 4, 256, 0, stream>>>(enc, cat, sq, maxg, hard);
    overlap2<<<BN / BI, 256, SMEM_BYTES, stream>>>(enc, sq, maxg, hard, kptr, out);
}

// Round 3
// 3025.585 us; speedup vs baseline: 1.1417x; 1.1417x over previous
//
#include <hip/hip_runtime.h>
#include <math.h>

#define BN 8192
#define ENC 256
#define NCL 32
#define TJ 64              // j-rows per LDS tile (lane-owns-j => 64)
#define BI 16              // i-rows per block (4 waves x 4)
#define RW 4               // i-rows per wave
#define LSTR 260           // padded LDS floats per j-row
#define NTILES (BN / TJ)   // 128
#define SMEM_FLOATS (TJ * LSTR)
#define SMEM_BYTES (SMEM_FLOATS * 4 + 4 * NCL * 4)   // ~67 KB -> 2 blocks/CU

// ---------------- K1: per-row sumsq, argmax/max of categorical (unchanged) ----------------
__global__ void prep_kernel(const float* __restrict__ enc, const float* __restrict__ cat,
                            float* __restrict__ sq, float* __restrict__ maxg,
                            int* __restrict__ hard) {
    int w = threadIdx.x >> 6, l = threadIdx.x & 63;
    int row = blockIdx.x * 4 + w;
    const float4* e4 = (const float4*)(enc + (size_t)row * ENC);
    float4 v = e4[l];
    float s = v.x * v.x + v.y * v.y + v.z * v.z + v.w * v.w;
    for (int m = 32; m; m >>= 1) s += __shfl_xor(s, m, 64);

    float cv = (l < NCL) ? cat[(size_t)row * NCL + l] : -__builtin_huge_valf();
    int ci = (l < NCL) ? l : 0x7fffffff;
    for (int m = 32; m; m >>= 1) {
        float ov = __shfl_xor(cv, m, 64);
        int oi = __shfl_xor(ci, m, 64);
        if (ov > cv || (ov == cv && oi < ci)) { cv = ov; ci = oi; }
    }
    if (l == 0) { sq[row] = s; maxg[row] = cv; hard[row] = ci; }
}

// ---------------- K2: streaming GEMM + exact top-(k+1), 2 blocks/CU for latency hiding ----------------
__global__ __launch_bounds__(256, 2)
void overlap3(const float* __restrict__ enc, const float* __restrict__ sq,
              const float* __restrict__ maxg, const int* __restrict__ hard,
              const int* __restrict__ kptr, float* __restrict__ out) {
    extern __shared__ float smem[];
    float* sB = smem;                          // TJ * LSTR floats (single buffer)
    int* sbins = (int*)(smem + SMEM_FLOATS);   // 4 waves x 32 bins

    const int t = threadIdx.x;
    const int l = t & 63;
    const int wu = __builtin_amdgcn_readfirstlane(t >> 6);
    const int i_base = blockIdx.x * BI + wu * RW;
    const int K1 = *kptr + 1;                  // 26

    float cand_d[RW], curT[RW];
    int cand_id[RW], curML[RW];
#pragma unroll
    for (int r = 0; r < RW; ++r) {
        cand_d[r] = __builtin_huge_valf();
        cand_id[r] = 0;
        curT[r] = __builtin_huge_valf();
        curML[r] = 0;
    }

    float sqi[RW];
#pragma unroll
    for (int r = 0; r < RW; ++r) sqi[r] = sq[i_base + r];   // wave-uniform -> scalar path

    const float* arow = enc + (size_t)i_base * ENC;

    // stage tile 0
    float4 pre[16];
#pragma unroll
    for (int it = 0; it < 16; ++it) {
        int idx = t + it * 256, r = idx >> 6, c = idx & 63;
        pre[it] = ((const float4*)enc)[(size_t)r * (ENC / 4) + c];
    }
#pragma unroll
    for (int it = 0; it < 16; ++it) {
        int idx = t + it * 256, r = idx >> 6, c = idx & 63;
        *(float4*)(sB + r * LSTR + c * 4) = pre[it];
    }
    __syncthreads();

    for (int tt = 0; tt < NTILES; ++tt) {
        const int j0 = tt * TJ;
        const int jn = (tt + 1 < NTILES) ? (tt + 1) * TJ : 0;

        // issue next-tile loads (if compiler sinks them, co-resident block hides the latency)
#pragma unroll
        for (int it = 0; it < 16; ++it) {
            int idx = t + it * 256, r = idx >> 6, c = idx & 63;
            pre[it] = ((const float4*)enc)[(size_t)(jn + r) * (ENC / 4) + c];
        }

        float sqj = sq[j0 + l];
        int cidl = hard[j0 + l];

        // GEMM: lane = j, k ascending float4 chain (bit-identical to rounds 1/2)
        float acc[RW];
#pragma unroll
        for (int r = 0; r < RW; ++r) acc[r] = 0.0f;
        const float* brow = sB + l * LSTR;
#pragma unroll 8
        for (int k4 = 0; k4 < ENC; k4 += 4) {
            float4 b = *(const float4*)(brow + k4);
#pragma unroll
            for (int r = 0; r < RW; ++r) {
                const float4 a = *(const float4*)(arow + r * ENC + k4);  // uniform -> s_load
                float s = acc[r];
                s = fmaf(b.x, a.x, s);
                s = fmaf(b.y, a.y, s);
                s = fmaf(b.z, a.z, s);
                s = fmaf(b.w, a.w, s);
                acc[r] = s;
            }
        }

        // exact top-K1 insertion with cluster payload (identical semantics to round 2)
#pragma unroll
        for (int r = 0; r < RW; ++r) {
            float d = sqrtf(fmaxf(sqi[r] + sqj - 2.0f * acc[r], 0.0f));
            unsigned long long m = __ballot(d < curT[r]);
            while (m) {
                int L = __ffsll(m) - 1;
                m &= m - 1;
                float v = __shfl(d, L, 64);
                if (v < curT[r]) {
                    int cid = __shfl(cidl, L, 64);
                    if (l == curML[r]) { cand_d[r] = v; cand_id[r] = cid; }
                    float mv = (l < K1) ? cand_d[r] : -1.0f;
                    int mi = l;
                    for (int s = 32; s; s >>= 1) {
                        float ov = __shfl_xor(mv, s, 64);
                        int oi = __shfl_xor(mi, s, 64);
                        if (ov > mv || (ov == mv && oi < mi)) { mv = ov; mi = oi; }
                    }
                    curT[r] = mv; curML[r] = mi;
                    m &= __ballot(d < mv);
                }
            }
        }

        __syncthreads();
#pragma unroll
        for (int it = 0; it < 16; ++it) {
            int idx = t + it * 256, r = idx >> 6, c = idx & 63;
            *(float4*)(sB + r * LSTR + c * 4) = pre[it];
        }
        __syncthreads();
    }

    // epilogue (identical math to rounds 1/2)
    int* mybins = sbins + wu * NCL;
#pragma unroll
    for (int r = 0; r < RW; ++r) {
        float mv = (l < K1) ? cand_d[r] : -1.0f;
        for (int s = 32; s; s >>= 1) {
            float ov = __shfl_xor(mv, s, 64);
            mv = (ov > mv) ? ov : mv;
        }
        float thr = mv;
        bool isn = (l < K1) && (cand_d[r] < thr);
        int n = __popcll(__ballot(isn));
        if (l < NCL) mybins[l] = 0;
        if (isn) atomicAdd(&mybins[cand_id[r]], 1);
        int cnt = (l < NCL) ? mybins[l] : 0;
        float nf = (float)n;
        float b = (float)cnt / nf;
        float term = (l < NCL) ? (-b * logf(b + 1e-5f)) : 0.0f;
        if (l < NCL) {
            for (int s = 16; s; s >>= 1) term += __shfl_xor(term, s, 64);
        }
        if (l == 0) out[i_base + r] = term * maxg[i_base + r];
    }
}

extern "C" void kernel_launch(void* const* d_in, const int* in_sizes, int n_in,
                              void* d_out, int out_size, void* d_ws, size_t ws_size,
                              hipStream_t stream) {
    const float* enc = (const float*)d_in[0];
    const float* cat = (const float*)d_in[1];
    const int* kptr = (const int*)d_in[2];
    float* out = (float*)d_out;

    float* sq = (float*)d_ws;
    float* maxg = sq + BN;
    int* hard = (int*)(maxg + BN);

    (void)hipFuncSetAttribute((const void*)overlap3,
                              hipFuncAttributeMaxDynamicSharedMemorySize, SMEM_BYTES);

    prep_kernel<<<BN / 4, 256, 0, stream>>>(enc, cat, sq, maxg, hard);
    overlap3<<<BN / BI, 256, SMEM_BYTES, stream>>>(enc, sq, maxg, hard, kptr, out);
}

// Round 4
// 2510.076 us; speedup vs baseline: 1.3762x; 1.2054x over previous
//
#include <hip/hip_runtime.h>
#include <math.h>

#define BN 8192
#define ENC 256
#define NCL 32
#define TJ 64              // j-rows per LDS tile (lane-owns-j)
#define BI 16              // i-rows per block (4 waves x 4)
#define RW 4               // i-rows per wave
#define NTILES (BN / TJ)   // 128
#define SMEM_FLOATS (TJ * ENC)                       // unpadded: global_load_lds requires contiguity
#define SMEM_BYTES (SMEM_FLOATS * 4 + 4 * NCL * 4)   // 64 KB + bins -> 2 blocks/CU

// async global->LDS, 16B per lane, lane i deposits at lds + i*16
#define GLDS16(g, l)                                                          \
    __builtin_amdgcn_global_load_lds(                                         \
        (const __attribute__((address_space(1))) void*)(g),                   \
        (__attribute__((address_space(3))) void*)(l), 16, 0, 0)

// ---------------- K1: per-row sumsq, argmax/max of categorical (unchanged) ----------------
__global__ void prep_kernel(const float* __restrict__ enc, const float* __restrict__ cat,
                            float* __restrict__ sq, float* __restrict__ maxg,
                            int* __restrict__ hard) {
    int w = threadIdx.x >> 6, l = threadIdx.x & 63;
    int row = blockIdx.x * 4 + w;
    const float4* e4 = (const float4*)(enc + (size_t)row * ENC);
    float4 v = e4[l];
    float s = v.x * v.x + v.y * v.y + v.z * v.z + v.w * v.w;
    for (int m = 32; m; m >>= 1) s += __shfl_xor(s, m, 64);

    float cv = (l < NCL) ? cat[(size_t)row * NCL + l] : -__builtin_huge_valf();
    int ci = (l < NCL) ? l : 0x7fffffff;
    for (int m = 32; m; m >>= 1) {
        float ov = __shfl_xor(cv, m, 64);
        int oi = __shfl_xor(ci, m, 64);
        if (ov > cv || (ov == cv && oi < ci)) { cv = ov; ci = oi; }
    }
    if (l == 0) { sq[row] = s; maxg[row] = cv; hard[row] = ci; }
}

// ---------------- K2: glds-staged streaming GEMM + exact top-(k+1) ----------------
__global__ __launch_bounds__(256, 2)
void overlap4(const float* __restrict__ enc, const float* __restrict__ sq,
              const float* __restrict__ maxg, const int* __restrict__ hard,
              const int* __restrict__ kptr, float* __restrict__ out) {
    extern __shared__ float smem[];
    float* sB = smem;                          // TJ*ENC floats, XOR-swizzled rows
    int* sbins = (int*)(smem + SMEM_FLOATS);

    const int t = threadIdx.x;
    const int l = t & 63;
    const int wu = __builtin_amdgcn_readfirstlane(t >> 6);
    const int i_base = blockIdx.x * BI + wu * RW;
    const int K1 = *kptr + 1;                  // 26

    float cand_d[RW], curT[RW];
    int cand_id[RW], curML[RW];
#pragma unroll
    for (int r = 0; r < RW; ++r) {
        cand_d[r] = __builtin_huge_valf();
        cand_id[r] = 0;
        curT[r] = __builtin_huge_valf();
        curML[r] = 0;
    }

    float sqi[RW];
#pragma unroll
    for (int r = 0; r < RW; ++r) sqi[r] = sq[i_base + r];   // uniform -> scalar

    const float* arow = enc + (size_t)i_base * ENC;
    const float4* enc4 = (const float4*)enc;

    // stage tile 0: wave wu stages rows wu*16..wu*16+15; source chunk permuted by row swizzle
#pragma unroll
    for (int rr = 0; rr < 16; ++rr) {
        int jr = wu * 16 + rr;
        GLDS16(enc4 + (size_t)jr * 64 + (l ^ (jr & 7)), sB + jr * ENC);
    }
    __syncthreads();

    for (int tt = 0; tt < NTILES; ++tt) {
        const int j0 = tt * TJ;

        float sqj = sq[j0 + l];
        int cidl = hard[j0 + l];

        // GEMM: lane = j-row l of tile; logical k ascends (q = k4/4), phys chunk = q ^ (l&7)
        float acc[RW];
#pragma unroll
        for (int r = 0; r < RW; ++r) acc[r] = 0.0f;
        const float* brow = sB + l * ENC;
        const int sw = (l & 7);
#pragma unroll 8
        for (int q = 0; q < ENC / 4; ++q) {
            float4 b = *(const float4*)(brow + ((q ^ sw) << 2));
            const int k4 = q << 2;
#pragma unroll
            for (int r = 0; r < RW; ++r) {
                const float4 a = *(const float4*)(arow + r * ENC + k4);  // uniform -> s_load
                float s = acc[r];
                s = fmaf(b.x, a.x, s);
                s = fmaf(b.y, a.y, s);
                s = fmaf(b.z, a.z, s);
                s = fmaf(b.w, a.w, s);
                acc[r] = s;
            }
        }

        // exact top-K1 insertion with cluster payload (identical to rounds 2/3)
#pragma unroll
        for (int r = 0; r < RW; ++r) {
            float d = sqrtf(fmaxf(sqi[r] + sqj - 2.0f * acc[r], 0.0f));
            unsigned long long m = __ballot(d < curT[r]);
            while (m) {
                int L = __ffsll(m) - 1;
                m &= m - 1;
                float v = __shfl(d, L, 64);
                if (v < curT[r]) {
                    int cid = __shfl(cidl, L, 64);
                    if (l == curML[r]) { cand_d[r] = v; cand_id[r] = cid; }
                    float mv = (l < K1) ? cand_d[r] : -1.0f;
                    int mi = l;
                    for (int s = 32; s; s >>= 1) {
                        float ov = __shfl_xor(mv, s, 64);
                        int oi = __shfl_xor(mi, s, 64);
                        if (ov > mv || (ov == mv && oi < mi)) { mv = ov; mi = oi; }
                    }
                    curT[r] = mv; curML[r] = mi;
                    m &= __ballot(d < mv);
                }
            }
        }

        __syncthreads();   // all waves done reading sB
        if (tt + 1 < NTILES) {
            const int jn = (tt + 1) * TJ;
#pragma unroll
            for (int rr = 0; rr < 16; ++rr) {
                int jr = wu * 16 + rr;
                GLDS16(enc4 + (size_t)(jn + jr) * 64 + (l ^ (jr & 7)), sB + jr * ENC);
            }
        }
        __syncthreads();   // staging drained (vmcnt(0) before barrier)
    }

    // epilogue (identical math to rounds 1-3)
    int* mybins = sbins + wu * NCL;
#pragma unroll
    for (int r = 0; r < RW; ++r) {
        float mv = (l < K1) ? cand_d[r] : -1.0f;
        for (int s = 32; s; s >>= 1) {
            float ov = __shfl_xor(mv, s, 64);
            mv = (ov > mv) ? ov : mv;
        }
        float thr = mv;
        bool isn = (l < K1) && (cand_d[r] < thr);
        int n = __popcll(__ballot(isn));
        if (l < NCL) mybins[l] = 0;
        if (isn) atomicAdd(&mybins[cand_id[r]], 1);
        int cnt = (l < NCL) ? mybins[l] : 0;
        float nf = (float)n;
        float b = (float)cnt / nf;
        float term = (l < NCL) ? (-b * logf(b + 1e-5f)) : 0.0f;
        if (l < NCL) {
            for (int s = 16; s; s >>= 1) term += __shfl_xor(term, s, 64);
        }
        if (l == 0) out[i_base + r] = term * maxg[i_base + r];
    }
}

extern "C" void kernel_launch(void* const* d_in, const int* in_sizes, int n_in,
                              void* d_out, int out_size, void* d_ws, size_t ws_size,
                              hipStream_t stream) {
    const float* enc = (const float*)d_in[0];
    const float* cat = (const float*)d_in[1];
    const int* kptr = (const int*)d_in[2];
    float* out = (float*)d_out;

    float* sq = (float*)d_ws;
    float* maxg = sq + BN;
    int* hard = (int*)(maxg + BN);

    (void)hipFuncSetAttribute((const void*)overlap4,
                              hipFuncAttributeMaxDynamicSharedMemorySize, SMEM_BYTES);

    prep_kernel<<<BN / 4, 256, 0, stream>>>(enc, cat, sq, maxg, hard);
    overlap4<<<BN / BI, 256, SMEM_BYTES, stream>>>(enc, sq, maxg, hard, kptr, out);
}

// Round 5
// 2305.856 us; speedup vs baseline: 1.4980x; 1.0886x over previous
//
#include <hip/hip_runtime.h>
#include <math.h>

#define BN 8192
#define ENC 256
#define NCL 32
#define TJ 64              // j-rows per LDS tile (lane-owns-j)
#define BI 16              // i-rows per block (4 waves x 4)
#define RW 4               // i-rows per wave
#define NTILES (BN / TJ)   // 128
#define SMEM_BYTES (TJ * ENC * 4)   // 64 KB exactly -> 2 blocks/CU

// ---------------- K1: per-row sumsq, argmax/max of categorical (unchanged) ----------------
__global__ void prep_kernel(const float* __restrict__ enc, const float* __restrict__ cat,
                            float* __restrict__ sq, float* __restrict__ maxg,
                            int* __restrict__ hard) {
    int w = threadIdx.x >> 6, l = threadIdx.x & 63;
    int row = blockIdx.x * 4 + w;
    const float4* e4 = (const float4*)(enc + (size_t)row * ENC);
    float4 v = e4[l];
    float s = v.x * v.x + v.y * v.y + v.z * v.z + v.w * v.w;
    for (int m = 32; m; m >>= 1) s += __shfl_xor(s, m, 64);

    float cv = (l < NCL) ? cat[(size_t)row * NCL + l] : -__builtin_huge_valf();
    int ci = (l < NCL) ? l : 0x7fffffff;
    for (int m = 32; m; m >>= 1) {
        float ov = __shfl_xor(cv, m, 64);
        int oi = __shfl_xor(ci, m, 64);
        if (ov > cv || (ov == cv && oi < ci)) { cv = ov; ci = oi; }
    }
    if (l == 0) { sq[row] = s; maxg[row] = cv; hard[row] = ci; }
}

__device__ __forceinline__ float rdlane(float v, int src) {
    return __int_as_float(__builtin_amdgcn_readlane(__float_as_int(v), src));
}

// ---------------- K2: LDS-B (rotated) + VGPR-A (readlane) streaming GEMM + exact top-(k+1) ----------------
__global__ __launch_bounds__(256, 2)
void overlap5(const float* __restrict__ enc, const float* __restrict__ sq,
              const float* __restrict__ maxg, const int* __restrict__ hard,
              const int* __restrict__ kptr, float* __restrict__ out) {
    extern __shared__ float sB[];   // [64 rows][64 chunks], chunk rotated by row: phys=(c+row)&63

    const int t = threadIdx.x;
    const int l = t & 63;
    const int wu = __builtin_amdgcn_readfirstlane(t >> 6);
    const int i_base = blockIdx.x * BI + wu * RW;
    const int K1 = *kptr + 1;       // 26

    // A distributed in VGPRs: lane l holds row (l>>4) of this wave's 4 i-rows,
    // floats (l&15)*16 .. +15  (16 VGPRs/lane = 4 rows x 1KB per wave)
    float af[16];
    {
        const float4* arow4 = (const float4*)(enc + (size_t)(i_base + (l >> 4)) * ENC) + (l & 15) * 4;
#pragma unroll
        for (int t4 = 0; t4 < 4; ++t4) {
            float4 v = arow4[t4];
            af[t4 * 4 + 0] = v.x; af[t4 * 4 + 1] = v.y;
            af[t4 * 4 + 2] = v.z; af[t4 * 4 + 3] = v.w;
        }
    }

    float cand_d[RW], curT[RW];
    int cand_id[RW], curML[RW];
#pragma unroll
    for (int r = 0; r < RW; ++r) {
        cand_d[r] = __builtin_huge_valf();
        cand_id[r] = 0;
        curT[r] = __builtin_huge_valf();
        curML[r] = 0;
    }

    float sqi[RW];
#pragma unroll
    for (int r = 0; r < RW; ++r) sqi[r] = sq[i_base + r];

    const float4* enc4 = (const float4*)enc;

    // stage tile 0 (ds_write path; rotation on write side)
    for (int s = 0; s < 16; ++s) {
        int e = t + 256 * s, row = e >> 6, c = e & 63;
        float4 v = enc4[(size_t)row * 64 + c];
        *(float4*)(sB + row * 256 + (((c + row) & 63) << 2)) = v;
    }
    __syncthreads();

    for (int tt = 0; tt < NTILES; ++tt) {
        const int j0 = tt * TJ;
        float sqj = sq[j0 + l];
        int cidl = hard[j0 + l];

        // GEMM: lane = j-row l; A via readlane (SGPR operand), B via rotated ds_read_b128.
        // Logical k ascends; fmaf chain bit-identical to rounds 1-4.
        float acc[RW];
#pragma unroll
        for (int r = 0; r < RW; ++r) acc[r] = 0.0f;
        const float* brow = sB + l * 256;
#pragma unroll 4
        for (int qq = 0; qq < 16; ++qq) {
#pragma unroll
            for (int qi = 0; qi < 4; ++qi) {
                const int q = qq * 4 + qi;
                float4 b = *(const float4*)(brow + (((q + l) & 63) << 2));
#pragma unroll
                for (int r = 0; r < RW; ++r) {
                    const int src = r * 16 + qq;
                    float a0 = rdlane(af[qi * 4 + 0], src);
                    float a1 = rdlane(af[qi * 4 + 1], src);
                    float a2 = rdlane(af[qi * 4 + 2], src);
                    float a3 = rdlane(af[qi * 4 + 3], src);
                    float s2 = acc[r];
                    s2 = fmaf(b.x, a0, s2);
                    s2 = fmaf(b.y, a1, s2);
                    s2 = fmaf(b.z, a2, s2);
                    s2 = fmaf(b.w, a3, s2);
                    acc[r] = s2;
                }
            }
        }

        // exact top-K1 insertion with cluster payload (identical to rounds 2-4)
#pragma unroll
        for (int r = 0; r < RW; ++r) {
            float d = sqrtf(fmaxf(sqi[r] + sqj - 2.0f * acc[r], 0.0f));
            unsigned long long m = __ballot(d < curT[r]);
            while (m) {
                int L = __ffsll(m) - 1;
                m &= m - 1;
                float v = __shfl(d, L, 64);
                if (v < curT[r]) {
                    int cid = __shfl(cidl, L, 64);
                    if (l == curML[r]) { cand_d[r] = v; cand_id[r] = cid; }
                    float mv = (l < K1) ? cand_d[r] : -1.0f;
                    int mi = l;
                    for (int s = 32; s; s >>= 1) {
                        float ov = __shfl_xor(mv, s, 64);
                        int oi = __shfl_xor(mi, s, 64);
                        if (ov > mv || (ov == mv && oi < mi)) { mv = ov; mi = oi; }
                    }
                    curT[r] = mv; curML[r] = mi;
                    m &= __ballot(d < mv);
                }
            }
        }

        __syncthreads();   // all waves done reading sB
        if (tt + 1 < NTILES) {
            const int jn = (tt + 1) * TJ;
            for (int s = 0; s < 16; ++s) {
                int e = t + 256 * s, row = e >> 6, c = e & 63;
                float4 v = enc4[(size_t)(jn + row) * 64 + c];
                *(float4*)(sB + row * 256 + (((c + row) & 63) << 2)) = v;
            }
        }
        __syncthreads();
    }

    // epilogue: ballot-based bins (no LDS, no atomics); float math identical to rounds 1-4
#pragma unroll
    for (int r = 0; r < RW; ++r) {
        float mv = (l < K1) ? cand_d[r] : -1.0f;
        for (int s = 32; s; s >>= 1) {
            float ov = __shfl_xor(mv, s, 64);
            mv = (ov > mv) ? ov : mv;
        }
        float thr = mv;
        bool isn = (l < K1) && (cand_d[r] < thr);
        int n = __popcll(__ballot(isn));
        int mycnt = 0;
        for (int c = 0; c < NCL; ++c) {
            int cc = __popcll(__ballot(isn && (cand_id[r] == c)));
            if (l == c) mycnt = cc;
        }
        float nf = (float)n;
        float b = (float)mycnt / nf;
        float term = (l < NCL) ? (-b * logf(b + 1e-5f)) : 0.0f;
        if (l < NCL) {
            for (int s = 16; s; s >>= 1) term += __shfl_xor(term, s, 64);
        }
        if (l == 0) out[i_base + r] = term * maxg[i_base + r];
    }
}

extern "C" void kernel_launch(void* const* d_in, const int* in_sizes, int n_in,
                              void* d_out, int out_size, void* d_ws, size_t ws_size,
                              hipStream_t stream) {
    const float* enc = (const float*)d_in[0];
    const float* cat = (const float*)d_in[1];
    const int* kptr = (const int*)d_in[2];
    float* out = (float*)d_out;

    float* sq = (float*)d_ws;
    float* maxg = sq + BN;
    int* hard = (int*)(maxg + BN);

    (void)hipFuncSetAttribute((const void*)overlap5,
                              hipFuncAttributeMaxDynamicSharedMemorySize, SMEM_BYTES);

    prep_kernel<<<BN / 4, 256, 0, stream>>>(enc, cat, sq, maxg, hard);
    overlap5<<<BN / BI, 256, SMEM_BYTES, stream>>>(enc, sq, maxg, hard, kptr, out);
}